// Round 2
// baseline (762.325 us; speedup 1.0000x reference)
//
#include <hip/hip_runtime.h>

#define DIM 64
#define NEG_SLOPE 0.01f

// ---------------------------------------------------------------------------
// Reference dtypes (per harness contract): id_embedding fp32 [N,64],
// edge_index int32 [2,E] (int64 in ref -> delivered as int32),
// weight_vector fp32 [2E,1]. Output fp32 [N,64].
//
// Symmetrized edge list: for e in [0,2E): src(e) = p[e mod 2E] = p[e] where
// p is the flat [2,E] array; dst(e) = p[e+E] for e<E else p[e-E].
//
// ws layout:
//   AGG : fp32 [N*DIM]  scatter accumulator            (51.2 MB)
//   CNT : u32  [N]      in-degree                      ( 0.8 MB)
//   INV : fp32 [N]      1/max(||x_row||,eps)           ( 0.8 MB)
// x1 lives in d_out between conv1 and the final kernel.
// ---------------------------------------------------------------------------

__global__ void k_normalize(const float* __restrict__ x,
                            float* __restrict__ inv, int N) {
    // one 64-lane wave per row
    int row  = blockIdx.x * 4 + (threadIdx.x >> 6);
    int lane = threadIdx.x & 63;
    if (row >= N) return;
    float v = x[(size_t)row * DIM + lane];
    float s = v * v;
    #pragma unroll
    for (int m = 32; m; m >>= 1) s += __shfl_xor(s, m, 64);
    if (lane == 0) inv[row] = 1.0f / fmaxf(sqrtf(s), 1e-12f);
}

__global__ void k_count(const int* __restrict__ p, unsigned* __restrict__ cnt,
                        int E) {
    int e = blockIdx.x * 256 + threadIdx.x;
    if (e >= 2 * E) return;
    int dst = (e < E) ? p[e + E] : p[e - E];
    atomicAdd(&cnt[dst], 1u);
}

// conv1: msg = (emb[src] * inv[src]) * w[e], scatter-add into agg
__global__ void k_scatter1(const float* __restrict__ emb,
                           const float* __restrict__ inv,
                           const int* __restrict__ p,
                           const float* __restrict__ w,
                           float* __restrict__ agg, int E) {
    int tid = blockIdx.x * 256 + threadIdx.x;   // 2E*64 = 76.8M < 2^31
    int e = tid >> 6;
    int d = tid & 63;
    if (e >= 2 * E) return;
    int src = p[e];
    int dst = (e < E) ? p[e + E] : p[e - E];
    float scale = w[e] * inv[src];
    float v = emb[(size_t)src * DIM + d] * scale;
    atomicAdd(&agg[(size_t)dst * DIM + d], v);
}

// conv2: msg = x1[src] * w[e]  (x1 already has leaky applied)
__global__ void k_scatter2(const float* __restrict__ x1,
                           const int* __restrict__ p,
                           const float* __restrict__ w,
                           float* __restrict__ agg, int E) {
    int tid = blockIdx.x * 256 + threadIdx.x;
    int e = tid >> 6;
    int d = tid & 63;
    if (e >= 2 * E) return;
    int src = p[e];
    int dst = (e < E) ? p[e + E] : p[e - E];
    float v = x1[(size_t)src * DIM + d] * w[e];
    atomicAdd(&agg[(size_t)dst * DIM + d], v);
}

__global__ void k_x1(const float* __restrict__ agg,
                     const unsigned* __restrict__ cnt,
                     float* __restrict__ x1, int N) {
    int i = blockIdx.x * 256 + threadIdx.x;
    if (i >= N * DIM) return;
    int row = i >> 6;
    float denom = fmaxf((float)cnt[row], 1.0f);
    float v = agg[i] / denom;
    v = (v >= 0.0f) ? v : NEG_SLOPE * v;
    x1[i] = v;
}

// out = x0 + x1 + x2   (x1 currently in `out`, x0 = emb*inv, x2 = leaky(agg/denom))
__global__ void k_final(const float* __restrict__ emb,
                        const float* __restrict__ inv,
                        const float* __restrict__ agg,
                        const unsigned* __restrict__ cnt,
                        float* __restrict__ out, int N) {
    int i = blockIdx.x * 256 + threadIdx.x;
    if (i >= N * DIM) return;
    int row = i >> 6;
    float denom = fmaxf((float)cnt[row], 1.0f);
    float x2 = agg[i] / denom;
    x2 = (x2 >= 0.0f) ? x2 : NEG_SLOPE * x2;
    float x0 = emb[i] * inv[row];
    out[i] = x0 + out[i] + x2;
}

extern "C" void kernel_launch(void* const* d_in, const int* in_sizes, int n_in,
                              void* d_out, int out_size, void* d_ws, size_t ws_size,
                              hipStream_t stream) {
    const int N = in_sizes[0] / DIM;      // 200000
    const int E = in_sizes[1] / 2;        // 600000

    const float* emb = (const float*)d_in[0];
    const int*   ei  = (const int*)d_in[1];
    const float* w   = (const float*)d_in[2];
    float*       out = (float*)d_out;

    char* ws = (char*)d_ws;
    float*    agg = (float*)ws;
    unsigned* cnt = (unsigned*)(ws + (size_t)N * DIM * 4);
    float*    inv = (float*)(ws + (size_t)N * DIM * 4 + (size_t)N * 4);

    const int nd_blocks = (N * DIM + 255) / 256;   // 50000
    const int e_blocks  = (2 * E + 255) / 256;     // 4688
    const int sc_blocks = (2 * E * DIM) / 256;     // 300000

    // zero AGG + CNT (contiguous in ws)
    hipMemsetAsync(agg, 0, (size_t)N * DIM * 4 + (size_t)N * 4, stream);

    k_normalize<<<(N + 3) / 4, 256, 0, stream>>>(emb, inv, N);
    k_count<<<e_blocks, 256, 0, stream>>>(ei, cnt, E);

    // conv1 -> x1 in d_out
    k_scatter1<<<sc_blocks, 256, 0, stream>>>(emb, inv, ei, w, agg, E);
    k_x1<<<nd_blocks, 256, 0, stream>>>(agg, cnt, out, N);

    // conv2
    hipMemsetAsync(agg, 0, (size_t)N * DIM * 4, stream);
    k_scatter2<<<sc_blocks, 256, 0, stream>>>(out, ei, w, agg, E);

    // out = x0 + x1 + x2
    k_final<<<nd_blocks, 256, 0, stream>>>(emb, inv, agg, cnt, out, N);
}

// Round 3
// 531.649 us; speedup vs baseline: 1.4339x; 1.4339x over previous
//
#include <hip/hip_runtime.h>

#define DIM 64
#define NEG_SLOPE 0.01f

// ---------------------------------------------------------------------------
// Round 3: scatter-atomics -> CSR gather.
// Round-2 evidence: each scatter conv wrote 300 MB (2E*64*4 B) through the
// fabric because device-coherent fp32 atomics can't be cached per-XCD.
// Gather reads are cacheable (x fits in 256 MB LLC) and writes are N*256 B
// coalesced. CSR (by dst) built on device each call.
//
// ws layout (16B-aligned sections):
//   X1      fp32   [N*DIM]   conv1 output (leaky applied)     51.2 MB
//   COLW    float2 [2E]      (src, weight) per CSR slot        9.6 MB
//   ROWPTR  u32    [N+1]
//   CURSOR  u32    [N]       fill cursors (copy of rowptr)
//   CNT     u32    [N]       degree counts (scan input)
//   INV     fp32   [N]       1/max(||emb_row||, eps)
//   BSUM    u32    [256]     scan block sums
// total ~64 MB.
// ---------------------------------------------------------------------------

__global__ void k_normalize(const float* __restrict__ x,
                            float* __restrict__ inv, int N) {
    int row  = blockIdx.x * 4 + (threadIdx.x >> 6);
    int lane = threadIdx.x & 63;
    if (row >= N) return;
    float v = x[(size_t)row * DIM + lane];
    float s = v * v;
    #pragma unroll
    for (int m = 32; m; m >>= 1) s += __shfl_xor(s, m, 64);
    if (lane == 0) inv[row] = 1.0f / fmaxf(sqrtf(s), 1e-12f);
}

__global__ void k_count(const int* __restrict__ p, unsigned* __restrict__ cnt,
                        int E) {
    int e = blockIdx.x * 256 + threadIdx.x;
    if (e >= 2 * E) return;
    int dst = (e < E) ? p[e + E] : p[e - E];
    atomicAdd(&cnt[dst], 1u);
}

// exclusive scan, stage 1: per-block (1024 elems) partial scan + block sums
__global__ void k_scan1(const unsigned* __restrict__ cnt,
                        unsigned* __restrict__ row_ptr,
                        unsigned* __restrict__ bsum, int N) {
    __shared__ unsigned sdata[256];
    int t = threadIdx.x;
    int base = blockIdx.x * 1024 + t * 4;
    unsigned v[4];
    #pragma unroll
    for (int k = 0; k < 4; k++) {
        int i = base + k;
        v[k] = (i < N) ? cnt[i] : 0u;
    }
    unsigned tsum = v[0] + v[1] + v[2] + v[3];
    sdata[t] = tsum;
    __syncthreads();
    for (int off = 1; off < 256; off <<= 1) {
        unsigned x = (t >= off) ? sdata[t - off] : 0u;
        __syncthreads();
        sdata[t] += x;
        __syncthreads();
    }
    unsigned texcl = sdata[t] - tsum;
    if (t == 255) bsum[blockIdx.x] = sdata[255];
    unsigned run = texcl;
    #pragma unroll
    for (int k = 0; k < 4; k++) {
        int i = base + k;
        if (i < N) row_ptr[i] = run;
        run += v[k];
    }
}

// stage 2: single block scans the (<=256) block sums; writes row_ptr[N]=total
__global__ void k_scan2(unsigned* __restrict__ bsum,
                        unsigned* __restrict__ row_ptr, int nb, int N) {
    __shared__ unsigned sdata[256];
    int t = threadIdx.x;
    unsigned v = (t < nb) ? bsum[t] : 0u;
    sdata[t] = v;
    __syncthreads();
    for (int off = 1; off < 256; off <<= 1) {
        unsigned x = (t >= off) ? sdata[t - off] : 0u;
        __syncthreads();
        sdata[t] += x;
        __syncthreads();
    }
    if (t < nb) bsum[t] = sdata[t] - v;       // exclusive
    if (t == 255) row_ptr[N] = sdata[255];    // total = 2E
}

// stage 3: add block offsets; also materialize fill cursors
__global__ void k_scan3(unsigned* __restrict__ row_ptr,
                        unsigned* __restrict__ cursor,
                        const unsigned* __restrict__ bsum, int N) {
    int i = blockIdx.x * 256 + threadIdx.x;
    if (i >= N) return;
    unsigned r = row_ptr[i] + bsum[i >> 10];
    row_ptr[i] = r;
    cursor[i]  = r;
}

__global__ void k_fill(const int* __restrict__ p, const float* __restrict__ w,
                       unsigned* __restrict__ cursor,
                       float2* __restrict__ colw, int E) {
    int e = blockIdx.x * 256 + threadIdx.x;
    if (e >= 2 * E) return;
    int src = p[e];
    int dst = (e < E) ? p[e + E] : p[e - E];
    unsigned pos = atomicAdd(&cursor[dst], 1u);
    colw[pos] = make_float2(__int_as_float(src), w[e]);
}

// conv1: x1 = leaky( mean_j( emb[src_j]*inv[src_j] * w_j ) )
__global__ void k_conv1(const float* __restrict__ emb,
                        const float* __restrict__ inv,
                        const unsigned* __restrict__ row_ptr,
                        const float2* __restrict__ colw,
                        float* __restrict__ x1, int N) {
    int row  = blockIdx.x * 4 + (threadIdx.x >> 6);
    int lane = threadIdx.x & 63;
    if (row >= N) return;
    unsigned s = row_ptr[row], e = row_ptr[row + 1];
    float acc = 0.0f;
    for (unsigned j = s; j < e; j++) {
        float2 cw = colw[j];
        int   src   = __float_as_int(cw.x);
        float scale = cw.y * inv[src];
        acc += emb[(size_t)src * DIM + lane] * scale;
    }
    float denom = fmaxf((float)(e - s), 1.0f);
    float v = acc / denom;
    x1[(size_t)row * DIM + lane] = (v >= 0.0f) ? v : NEG_SLOPE * v;
}

// conv2 + epilogue: out = emb*inv + x1 + leaky( mean_j( x1[src_j]*w_j ) )
__global__ void k_conv2(const float* __restrict__ emb,
                        const float* __restrict__ inv,
                        const float* __restrict__ x1,
                        const unsigned* __restrict__ row_ptr,
                        const float2* __restrict__ colw,
                        float* __restrict__ out, int N) {
    int row  = blockIdx.x * 4 + (threadIdx.x >> 6);
    int lane = threadIdx.x & 63;
    if (row >= N) return;
    unsigned s = row_ptr[row], e = row_ptr[row + 1];
    float acc = 0.0f;
    for (unsigned j = s; j < e; j++) {
        float2 cw = colw[j];
        int src = __float_as_int(cw.x);
        acc += x1[(size_t)src * DIM + lane] * cw.y;
    }
    float denom = fmaxf((float)(e - s), 1.0f);
    float x2 = acc / denom;
    x2 = (x2 >= 0.0f) ? x2 : NEG_SLOPE * x2;
    size_t i = (size_t)row * DIM + lane;
    out[i] = emb[i] * inv[row] + x1[i] + x2;
}

static inline size_t align16(size_t x) { return (x + 15) & ~(size_t)15; }

extern "C" void kernel_launch(void* const* d_in, const int* in_sizes, int n_in,
                              void* d_out, int out_size, void* d_ws, size_t ws_size,
                              hipStream_t stream) {
    const int N = in_sizes[0] / DIM;      // 200000
    const int E = in_sizes[1] / 2;        // 600000

    const float* emb = (const float*)d_in[0];
    const int*   ei  = (const int*)d_in[1];
    const float* w   = (const float*)d_in[2];
    float*       out = (float*)d_out;

    char* ws = (char*)d_ws;
    size_t off = 0;
    float*    x1      = (float*)(ws + off);    off += align16((size_t)N * DIM * 4);
    float2*   colw    = (float2*)(ws + off);   off += align16((size_t)2 * E * 8);
    unsigned* row_ptr = (unsigned*)(ws + off); off += align16((size_t)(N + 1) * 4);
    unsigned* cursor  = (unsigned*)(ws + off); off += align16((size_t)N * 4);
    unsigned* cnt     = (unsigned*)(ws + off); off += align16((size_t)N * 4);
    float*    inv     = (float*)(ws + off);    off += align16((size_t)N * 4);
    unsigned* bsum    = (unsigned*)(ws + off); off += align16(256 * 4);

    const int e_blocks  = (2 * E + 255) / 256;     // 4688
    const int row_blocks = (N + 3) / 4;            // 50000
    const int nb = (N + 1023) / 1024;              // 196 scan blocks

    hipMemsetAsync(cnt, 0, (size_t)N * 4, stream);

    k_normalize<<<row_blocks, 256, 0, stream>>>(emb, inv, N);
    k_count<<<e_blocks, 256, 0, stream>>>(ei, cnt, E);
    k_scan1<<<nb, 256, 0, stream>>>(cnt, row_ptr, bsum, N);
    k_scan2<<<1, 256, 0, stream>>>(bsum, row_ptr, nb, N);
    k_scan3<<<(N + 255) / 256, 256, 0, stream>>>(row_ptr, cursor, bsum, N);
    k_fill<<<e_blocks, 256, 0, stream>>>(ei, w, cursor, colw, E);

    k_conv1<<<row_blocks, 256, 0, stream>>>(emb, inv, row_ptr, colw, x1, N);
    k_conv2<<<row_blocks, 256, 0, stream>>>(emb, inv, x1, row_ptr, colw, out, N);
}

// Round 4
// 387.834 us; speedup vs baseline: 1.9656x; 1.3708x over previous
//
#include <hip/hip_runtime.h>

#define DIM 64
#define NEG_SLOPE 0.01f

// ---------------------------------------------------------------------------
// Round 4: latency-bound gather convs -> MLP-maximized gather.
//   * colw chunk-preloaded lane-parallel, broadcast by __shfl (no serial
//     uniform loads in the edge loop)
//   * gather unrolled x4: 4 independent 256B row loads in flight
//   * conv1 weight pre-scaled by inv[src] at fill time (no inv gather in loop)
//
// ws layout (16B-aligned):
//   X1     fp32   [N*DIM]  conv1 output                     51.2 MB
//   COLW1  float2 [2E]     (src, w*inv[src])  for conv1      9.6 MB
//   COLW2  float2 [2E]     (src, w)           for conv2      9.6 MB
//   ROWPTR u32 [N+1], CURSOR u32 [N], CNT u32 [N], INV fp32 [N], BSUM u32[256]
// total ~73.7 MB.
// ---------------------------------------------------------------------------

__global__ void k_normalize(const float* __restrict__ x,
                            float* __restrict__ inv, int N) {
    int row  = blockIdx.x * 4 + (threadIdx.x >> 6);
    int lane = threadIdx.x & 63;
    if (row >= N) return;
    float v = x[(size_t)row * DIM + lane];
    float s = v * v;
    #pragma unroll
    for (int m = 32; m; m >>= 1) s += __shfl_xor(s, m, 64);
    if (lane == 0) inv[row] = 1.0f / fmaxf(sqrtf(s), 1e-12f);
}

__global__ void k_count(const int* __restrict__ p, unsigned* __restrict__ cnt,
                        int E) {
    int e = blockIdx.x * 256 + threadIdx.x;
    if (e >= 2 * E) return;
    int dst = (e < E) ? p[e + E] : p[e - E];
    atomicAdd(&cnt[dst], 1u);
}

__global__ void k_scan1(const unsigned* __restrict__ cnt,
                        unsigned* __restrict__ row_ptr,
                        unsigned* __restrict__ bsum, int N) {
    __shared__ unsigned sdata[256];
    int t = threadIdx.x;
    int base = blockIdx.x * 1024 + t * 4;
    unsigned v[4];
    #pragma unroll
    for (int k = 0; k < 4; k++) {
        int i = base + k;
        v[k] = (i < N) ? cnt[i] : 0u;
    }
    unsigned tsum = v[0] + v[1] + v[2] + v[3];
    sdata[t] = tsum;
    __syncthreads();
    for (int off = 1; off < 256; off <<= 1) {
        unsigned x = (t >= off) ? sdata[t - off] : 0u;
        __syncthreads();
        sdata[t] += x;
        __syncthreads();
    }
    unsigned texcl = sdata[t] - tsum;
    if (t == 255) bsum[blockIdx.x] = sdata[255];
    unsigned run = texcl;
    #pragma unroll
    for (int k = 0; k < 4; k++) {
        int i = base + k;
        if (i < N) row_ptr[i] = run;
        run += v[k];
    }
}

__global__ void k_scan2(unsigned* __restrict__ bsum,
                        unsigned* __restrict__ row_ptr, int nb, int N) {
    __shared__ unsigned sdata[256];
    int t = threadIdx.x;
    unsigned v = (t < nb) ? bsum[t] : 0u;
    sdata[t] = v;
    __syncthreads();
    for (int off = 1; off < 256; off <<= 1) {
        unsigned x = (t >= off) ? sdata[t - off] : 0u;
        __syncthreads();
        sdata[t] += x;
        __syncthreads();
    }
    if (t < nb) bsum[t] = sdata[t] - v;
    if (t == 255) row_ptr[N] = sdata[255];
}

__global__ void k_scan3(unsigned* __restrict__ row_ptr,
                        unsigned* __restrict__ cursor,
                        const unsigned* __restrict__ bsum, int N) {
    int i = blockIdx.x * 256 + threadIdx.x;
    if (i >= N) return;
    unsigned r = row_ptr[i] + bsum[i >> 10];
    row_ptr[i] = r;
    cursor[i]  = r;
}

__global__ void k_fill(const int* __restrict__ p, const float* __restrict__ w,
                       const float* __restrict__ inv,
                       unsigned* __restrict__ cursor,
                       float2* __restrict__ colw1,
                       float2* __restrict__ colw2, int E) {
    int e = blockIdx.x * 256 + threadIdx.x;
    if (e >= 2 * E) return;
    int src = p[e];
    int dst = (e < E) ? p[e + E] : p[e - E];
    unsigned pos = atomicAdd(&cursor[dst], 1u);
    float wv = w[e];
    float sf = __int_as_float(src);
    colw1[pos] = make_float2(sf, wv * inv[src]);
    colw2[pos] = make_float2(sf, wv);
}

// sum_j x[src_j * DIM + lane] * w_j  with chunked colw preload + x4 MLP
__device__ __forceinline__ float gather_row_sum(const float* __restrict__ x,
                                                const float2* __restrict__ colw,
                                                unsigned s, unsigned e, int lane) {
    float acc = 0.0f;
    for (unsigned base = s; base < e; base += 64) {
        unsigned m = e - base; if (m > 64u) m = 64u;
        float2 cw = make_float2(0.0f, 0.0f);
        if ((unsigned)lane < m) cw = colw[base + lane];
        int   cx = __float_as_int(cw.x);
        float cy = cw.y;
        unsigned j = 0;
        for (; j + 4 <= m; j += 4) {
            int   s0 = __shfl(cx, (int)j);
            int   s1 = __shfl(cx, (int)j + 1);
            int   s2 = __shfl(cx, (int)j + 2);
            int   s3 = __shfl(cx, (int)j + 3);
            float w0 = __shfl(cy, (int)j);
            float w1 = __shfl(cy, (int)j + 1);
            float w2 = __shfl(cy, (int)j + 2);
            float w3 = __shfl(cy, (int)j + 3);
            float v0 = x[(size_t)s0 * DIM + lane];
            float v1 = x[(size_t)s1 * DIM + lane];
            float v2 = x[(size_t)s2 * DIM + lane];
            float v3 = x[(size_t)s3 * DIM + lane];
            acc += v0 * w0; acc += v1 * w1; acc += v2 * w2; acc += v3 * w3;
        }
        for (; j < m; j++) {
            int   sj = __shfl(cx, (int)j);
            float wj = __shfl(cy, (int)j);
            acc += x[(size_t)sj * DIM + lane] * wj;
        }
    }
    return acc;
}

__global__ void k_conv1(const float* __restrict__ emb,
                        const unsigned* __restrict__ row_ptr,
                        const float2* __restrict__ colw1,
                        float* __restrict__ x1, int N) {
    int row  = blockIdx.x * 4 + (threadIdx.x >> 6);
    int lane = threadIdx.x & 63;
    if (row >= N) return;
    unsigned s = row_ptr[row], e = row_ptr[row + 1];
    float acc = gather_row_sum(emb, colw1, s, e, lane);
    float v = acc / fmaxf((float)(e - s), 1.0f);
    x1[(size_t)row * DIM + lane] = (v >= 0.0f) ? v : NEG_SLOPE * v;
}

__global__ void k_conv2(const float* __restrict__ emb,
                        const float* __restrict__ inv,
                        const float* __restrict__ x1,
                        const unsigned* __restrict__ row_ptr,
                        const float2* __restrict__ colw2,
                        float* __restrict__ out, int N) {
    int row  = blockIdx.x * 4 + (threadIdx.x >> 6);
    int lane = threadIdx.x & 63;
    if (row >= N) return;
    unsigned s = row_ptr[row], e = row_ptr[row + 1];
    float acc = gather_row_sum(x1, colw2, s, e, lane);
    float x2 = acc / fmaxf((float)(e - s), 1.0f);
    x2 = (x2 >= 0.0f) ? x2 : NEG_SLOPE * x2;
    size_t i = (size_t)row * DIM + lane;
    out[i] = emb[i] * inv[row] + x1[i] + x2;
}

static inline size_t align16(size_t x) { return (x + 15) & ~(size_t)15; }

extern "C" void kernel_launch(void* const* d_in, const int* in_sizes, int n_in,
                              void* d_out, int out_size, void* d_ws, size_t ws_size,
                              hipStream_t stream) {
    const int N = in_sizes[0] / DIM;      // 200000
    const int E = in_sizes[1] / 2;        // 600000

    const float* emb = (const float*)d_in[0];
    const int*   ei  = (const int*)d_in[1];
    const float* w   = (const float*)d_in[2];
    float*       out = (float*)d_out;

    char* ws = (char*)d_ws;
    size_t off = 0;
    float*    x1      = (float*)(ws + off);    off += align16((size_t)N * DIM * 4);
    float2*   colw1   = (float2*)(ws + off);   off += align16((size_t)2 * E * 8);
    float2*   colw2   = (float2*)(ws + off);   off += align16((size_t)2 * E * 8);
    unsigned* row_ptr = (unsigned*)(ws + off); off += align16((size_t)(N + 1) * 4);
    unsigned* cursor  = (unsigned*)(ws + off); off += align16((size_t)N * 4);
    unsigned* cnt     = (unsigned*)(ws + off); off += align16((size_t)N * 4);
    float*    inv     = (float*)(ws + off);    off += align16((size_t)N * 4);
    unsigned* bsum    = (unsigned*)(ws + off); off += align16(256 * 4);

    const int e_blocks   = (2 * E + 255) / 256;   // 4688
    const int row_blocks = (N + 3) / 4;           // 50000
    const int nb = (N + 1023) / 1024;             // 196

    hipMemsetAsync(cnt, 0, (size_t)N * 4, stream);

    k_normalize<<<row_blocks, 256, 0, stream>>>(emb, inv, N);
    k_count<<<e_blocks, 256, 0, stream>>>(ei, cnt, E);
    k_scan1<<<nb, 256, 0, stream>>>(cnt, row_ptr, bsum, N);
    k_scan2<<<1, 256, 0, stream>>>(bsum, row_ptr, nb, N);
    k_scan3<<<(N + 255) / 256, 256, 0, stream>>>(row_ptr, cursor, bsum, N);
    k_fill<<<e_blocks, 256, 0, stream>>>(ei, w, inv, cursor, colw1, colw2, E);

    k_conv1<<<row_blocks, 256, 0, stream>>>(emb, row_ptr, colw1, x1, N);
    k_conv2<<<row_blocks, 256, 0, stream>>>(emb, inv, x1, row_ptr, colw2, out, N);
}

// Round 5
// 350.010 us; speedup vs baseline: 2.1780x; 1.1081x over previous
//
#include <hip/hip_runtime.h>

#define DIM 64
#define NEG_SLOPE 0.01f

// ---------------------------------------------------------------------------
// Round 5: fill was write-scatter bound (115 MB HBM WRITE for 19.2 MB of
// arrays -> ~48 B per random partial-line store; traffic ~ #stores).
//   * single packed colw u32: src(18b) << 14 | w_fixed14  (1.2M x 4B stores)
//   * fill atomic removed: rank[e] recorded during count (coalesced),
//     pos = row_ptr[dst] + rank[e]
//   * conv1 re-scales with lane-parallel inv[src] gather (800 KB, L2-hit)
//   * normalize + count fused into one kernel
//
// ws layout (16B-aligned):
//   X1     fp32 [N*DIM]  conv1 output                 51.2 MB
//   COLW   u32  [2E]     packed (src, w14)             4.8 MB
//   RANK   u32  [2E]     per-edge rank within dst      4.8 MB
//   ROWPTR u32  [N+1], CNT u32 [N], INV fp32 [N], BSUM u32 [256]
// total ~63 MB.
// ---------------------------------------------------------------------------

__global__ void k_norm_count(const float* __restrict__ x,
                             float* __restrict__ inv,
                             const int* __restrict__ p,
                             unsigned* __restrict__ cnt,
                             unsigned* __restrict__ rank,
                             int N, int E, int row_blocks) {
    if ((int)blockIdx.x < row_blocks) {
        int row  = blockIdx.x * 4 + (threadIdx.x >> 6);
        int lane = threadIdx.x & 63;
        if (row >= N) return;
        float v = x[(size_t)row * DIM + lane];
        float s = v * v;
        #pragma unroll
        for (int m = 32; m; m >>= 1) s += __shfl_xor(s, m, 64);
        if (lane == 0) inv[row] = 1.0f / fmaxf(sqrtf(s), 1e-12f);
    } else {
        int e = (blockIdx.x - row_blocks) * 256 + threadIdx.x;
        if (e >= 2 * E) return;
        int dst = (e < E) ? p[e + E] : p[e - E];
        rank[e] = atomicAdd(&cnt[dst], 1u);
    }
}

__global__ void k_scan1(const unsigned* __restrict__ cnt,
                        unsigned* __restrict__ row_ptr,
                        unsigned* __restrict__ bsum, int N) {
    __shared__ unsigned sdata[256];
    int t = threadIdx.x;
    int base = blockIdx.x * 1024 + t * 4;
    unsigned v[4];
    #pragma unroll
    for (int k = 0; k < 4; k++) {
        int i = base + k;
        v[k] = (i < N) ? cnt[i] : 0u;
    }
    unsigned tsum = v[0] + v[1] + v[2] + v[3];
    sdata[t] = tsum;
    __syncthreads();
    for (int off = 1; off < 256; off <<= 1) {
        unsigned x = (t >= off) ? sdata[t - off] : 0u;
        __syncthreads();
        sdata[t] += x;
        __syncthreads();
    }
    unsigned texcl = sdata[t] - tsum;
    if (t == 255) bsum[blockIdx.x] = sdata[255];
    unsigned run = texcl;
    #pragma unroll
    for (int k = 0; k < 4; k++) {
        int i = base + k;
        if (i < N) row_ptr[i] = run;
        run += v[k];
    }
}

__global__ void k_scan2(unsigned* __restrict__ bsum,
                        unsigned* __restrict__ row_ptr, int nb, int N) {
    __shared__ unsigned sdata[256];
    int t = threadIdx.x;
    unsigned v = (t < nb) ? bsum[t] : 0u;
    sdata[t] = v;
    __syncthreads();
    for (int off = 1; off < 256; off <<= 1) {
        unsigned x = (t >= off) ? sdata[t - off] : 0u;
        __syncthreads();
        sdata[t] += x;
        __syncthreads();
    }
    if (t < nb) bsum[t] = sdata[t] - v;
    if (t == 255) row_ptr[N] = sdata[255];
}

__global__ void k_scan3(unsigned* __restrict__ row_ptr,
                        const unsigned* __restrict__ bsum, int N) {
    int i = blockIdx.x * 256 + threadIdx.x;
    if (i >= N) return;
    row_ptr[i] += bsum[i >> 10];
}

// pos = row_ptr[dst] + rank[e]; colw[pos] = src<<14 | round(w*16384)
__global__ void k_fill(const int* __restrict__ p, const float* __restrict__ w,
                       const unsigned* __restrict__ row_ptr,
                       const unsigned* __restrict__ rank,
                       unsigned* __restrict__ colw, int E) {
    int e = blockIdx.x * 256 + threadIdx.x;
    if (e >= 2 * E) return;
    int src = p[e];
    int dst = (e < E) ? p[e + E] : p[e - E];
    unsigned pos = row_ptr[dst] + rank[e];
    unsigned w14 = (unsigned)(w[e] * 16384.0f + 0.5f);
    if (w14 > 16383u) w14 = 16383u;
    colw[pos] = ((unsigned)src << 14) | w14;
}

// sum_j x[src_j*DIM+lane] * w_j ; USE_INV multiplies w_j by inv[src_j]
template <bool USE_INV>
__device__ __forceinline__ float gather_row_sum(const float* __restrict__ x,
                                                const float* __restrict__ inv,
                                                const unsigned* __restrict__ colw,
                                                unsigned s, unsigned e, int lane) {
    float acc = 0.0f;
    for (unsigned base = s; base < e; base += 64) {
        unsigned m = e - base; if (m > 64u) m = 64u;
        unsigned u = 0;
        if ((unsigned)lane < m) u = colw[base + lane];
        int   cx = (int)(u >> 14);
        float cy = (float)(u & 16383u) * (1.0f / 16384.0f);
        if (USE_INV && (unsigned)lane < m) cy *= inv[cx];
        unsigned j = 0;
        for (; j + 4 <= m; j += 4) {
            int   s0 = __shfl(cx, (int)j);
            int   s1 = __shfl(cx, (int)j + 1);
            int   s2 = __shfl(cx, (int)j + 2);
            int   s3 = __shfl(cx, (int)j + 3);
            float w0 = __shfl(cy, (int)j);
            float w1 = __shfl(cy, (int)j + 1);
            float w2 = __shfl(cy, (int)j + 2);
            float w3 = __shfl(cy, (int)j + 3);
            float v0 = x[(size_t)s0 * DIM + lane];
            float v1 = x[(size_t)s1 * DIM + lane];
            float v2 = x[(size_t)s2 * DIM + lane];
            float v3 = x[(size_t)s3 * DIM + lane];
            acc += v0 * w0; acc += v1 * w1; acc += v2 * w2; acc += v3 * w3;
        }
        for (; j < m; j++) {
            int   sj = __shfl(cx, (int)j);
            float wj = __shfl(cy, (int)j);
            acc += x[(size_t)sj * DIM + lane] * wj;
        }
    }
    return acc;
}

__global__ void k_conv1(const float* __restrict__ emb,
                        const float* __restrict__ inv,
                        const unsigned* __restrict__ row_ptr,
                        const unsigned* __restrict__ colw,
                        float* __restrict__ x1, int N) {
    int row  = blockIdx.x * 4 + (threadIdx.x >> 6);
    int lane = threadIdx.x & 63;
    if (row >= N) return;
    unsigned s = row_ptr[row], e = row_ptr[row + 1];
    float acc = gather_row_sum<true>(emb, inv, colw, s, e, lane);
    float v = acc / fmaxf((float)(e - s), 1.0f);
    x1[(size_t)row * DIM + lane] = (v >= 0.0f) ? v : NEG_SLOPE * v;
}

__global__ void k_conv2(const float* __restrict__ emb,
                        const float* __restrict__ inv,
                        const float* __restrict__ x1,
                        const unsigned* __restrict__ row_ptr,
                        const unsigned* __restrict__ colw,
                        float* __restrict__ out, int N) {
    int row  = blockIdx.x * 4 + (threadIdx.x >> 6);
    int lane = threadIdx.x & 63;
    if (row >= N) return;
    unsigned s = row_ptr[row], e = row_ptr[row + 1];
    float acc = gather_row_sum<false>(x1, nullptr, colw, s, e, lane);
    float x2 = acc / fmaxf((float)(e - s), 1.0f);
    x2 = (x2 >= 0.0f) ? x2 : NEG_SLOPE * x2;
    size_t i = (size_t)row * DIM + lane;
    out[i] = emb[i] * inv[row] + x1[i] + x2;
}

static inline size_t align16(size_t x) { return (x + 15) & ~(size_t)15; }

extern "C" void kernel_launch(void* const* d_in, const int* in_sizes, int n_in,
                              void* d_out, int out_size, void* d_ws, size_t ws_size,
                              hipStream_t stream) {
    const int N = in_sizes[0] / DIM;      // 200000
    const int E = in_sizes[1] / 2;        // 600000

    const float* emb = (const float*)d_in[0];
    const int*   ei  = (const int*)d_in[1];
    const float* w   = (const float*)d_in[2];
    float*       out = (float*)d_out;

    char* ws = (char*)d_ws;
    size_t off = 0;
    float*    x1      = (float*)(ws + off);    off += align16((size_t)N * DIM * 4);
    unsigned* colw    = (unsigned*)(ws + off); off += align16((size_t)2 * E * 4);
    unsigned* rank    = (unsigned*)(ws + off); off += align16((size_t)2 * E * 4);
    unsigned* row_ptr = (unsigned*)(ws + off); off += align16((size_t)(N + 1) * 4);
    unsigned* cnt     = (unsigned*)(ws + off); off += align16((size_t)N * 4);
    float*    inv     = (float*)(ws + off);    off += align16((size_t)N * 4);
    unsigned* bsum    = (unsigned*)(ws + off); off += align16(256 * 4);

    const int e_blocks   = (2 * E + 255) / 256;   // 4688
    const int row_blocks = (N + 3) / 4;           // 50000
    const int nb = (N + 1023) / 1024;             // 196

    hipMemsetAsync(cnt, 0, (size_t)N * 4, stream);

    k_norm_count<<<row_blocks + e_blocks, 256, 0, stream>>>(
        emb, inv, ei, cnt, rank, N, E, row_blocks);
    k_scan1<<<nb, 256, 0, stream>>>(cnt, row_ptr, bsum, N);
    k_scan2<<<1, 256, 0, stream>>>(bsum, row_ptr, nb, N);
    k_scan3<<<(N + 255) / 256, 256, 0, stream>>>(row_ptr, bsum, N);
    k_fill<<<e_blocks, 256, 0, stream>>>(ei, w, row_ptr, rank, colw, E);

    k_conv1<<<row_blocks, 256, 0, stream>>>(emb, inv, row_ptr, colw, x1, N);
    k_conv2<<<row_blocks, 256, 0, stream>>>(emb, inv, x1, row_ptr, colw, out, N);
}

// Round 6
// 330.714 us; speedup vs baseline: 2.3051x; 1.0583x over previous
//
#include <hip/hip_runtime.h>
#include <hip/hip_fp16.h>

#define DIM 64
#define NEG_SLOPE 0.01f
#define BKT 512          // nodes per bucket (LDS bins in k_bucket)
#define TILE 2048        // edges per block in hist/place (scan tile too)

typedef unsigned u32;
typedef unsigned long long u64;

// ---------------------------------------------------------------------------
// Round 6: kill the global atomic histogram (measured ~60 ns per random-line
// RMW -> ~75 us for 1.2M) with an atomic-free two-level bucket CSR build:
//   k_norm_hist : normalize -> x0h (half) ; per-tile LDS hist -> mat[bin][blk]
//   scan1/scan2 : flat exclusive scan of mat (block offsets folded into users)
//   k_place     : re-rank via LDS cursors, write packed u64 to bucket segment
//   k_bucket    : per-bucket LDS counting sort -> row_ptr + colw (no atomics
//                 beyond LDS; global stores confined to small ranges)
// Convs gather fp16 rows (128 B/row) with 8-deep MLP.
//
// ws: x0h 25.6 + x1h 25.6 + places 9.6 + colw 4.8 + mat 0.92 + mscan 0.92
//     + row_ptr + bsum  ~= 68 MB
// ---------------------------------------------------------------------------

__global__ void k_norm_hist(const float* __restrict__ emb,
                            __half* __restrict__ x0h,
                            const int* __restrict__ p,
                            u32* __restrict__ mat,
                            int N, int E, int rb, int B, int nblkE) {
    if ((int)blockIdx.x < rb) {
        int row  = blockIdx.x * 4 + (threadIdx.x >> 6);
        int lane = threadIdx.x & 63;
        if (row >= N) return;
        float v = emb[(size_t)row * DIM + lane];
        float s = v * v;
        #pragma unroll
        for (int m = 32; m; m >>= 1) s += __shfl_xor(s, m, 64);
        float inv = 1.0f / fmaxf(sqrtf(s), 1e-12f);
        x0h[(size_t)row * DIM + lane] = __float2half(v * inv);
    } else {
        __shared__ u32 hist[BKT];
        int blk = blockIdx.x - rb;
        int t = threadIdx.x;
        for (int i = t; i < B; i += 256) hist[i] = 0;
        __syncthreads();
        int base = blk * TILE;
        #pragma unroll
        for (int k = 0; k < TILE / 256; k++) {
            int e = base + k * 256 + t;
            if (e < 2 * E) {
                int dst = (e < E) ? p[e + E] : p[e - E];
                atomicAdd(&hist[(u32)dst >> 9], 1u);
            }
        }
        __syncthreads();
        for (int i = t; i < B; i += 256) mat[(size_t)i * nblkE + blk] = hist[i];
    }
}

// exclusive scan over M elems, tile 2048 (256 thr x 8)
__global__ void k_scan1(const u32* __restrict__ in, u32* __restrict__ out,
                        u32* __restrict__ bsum, int M) {
    __shared__ u32 sdata[256];
    int t = threadIdx.x;
    int base = blockIdx.x * TILE + t * 8;
    u32 v[8]; u32 tsum = 0;
    #pragma unroll
    for (int k = 0; k < 8; k++) {
        int i = base + k;
        v[k] = (i < M) ? in[i] : 0u;
        tsum += v[k];
    }
    sdata[t] = tsum;
    __syncthreads();
    for (int off = 1; off < 256; off <<= 1) {
        u32 x = (t >= off) ? sdata[t - off] : 0u;
        __syncthreads();
        sdata[t] += x;
        __syncthreads();
    }
    u32 run = sdata[t] - tsum;
    if (t == 255) bsum[blockIdx.x] = sdata[255];
    #pragma unroll
    for (int k = 0; k < 8; k++) {
        int i = base + k;
        if (i < M) out[i] = run;
        run += v[k];
    }
}

__global__ void k_scan2(u32* __restrict__ bsum, int nb) {
    __shared__ u32 sdata[256];
    int t = threadIdx.x;
    u32 v = (t < nb) ? bsum[t] : 0u;
    sdata[t] = v;
    __syncthreads();
    for (int off = 1; off < 256; off <<= 1) {
        u32 x = (t >= off) ? sdata[t - off] : 0u;
        __syncthreads();
        sdata[t] += x;
        __syncthreads();
    }
    if (t < nb) bsum[t] = sdata[t] - v;
}

// place packed (dst_low9, src18, w14) into bucket-major order
__global__ void k_place(const int* __restrict__ p, const float* __restrict__ w,
                        const u32* __restrict__ mscan,
                        const u32* __restrict__ bsum,
                        u64* __restrict__ places, int E, int nblkE) {
    __shared__ u32 cur[BKT];
    int blk = blockIdx.x;
    int t = threadIdx.x;
    for (int i = t; i < BKT; i += 256) cur[i] = 0;
    __syncthreads();
    int base = blk * TILE;
    #pragma unroll
    for (int k = 0; k < TILE / 256; k++) {
        int e = base + k * 256 + t;
        if (e >= 2 * E) continue;
        int src = p[e];
        int dst = (e < E) ? p[e + E] : p[e - E];
        u32 bin = (u32)dst >> 9;
        u32 w14 = (u32)(w[e] * 16384.0f + 0.5f);
        if (w14 > 16383u) w14 = 16383u;
        u32 rank = atomicAdd(&cur[bin], 1u);
        size_t flat = (size_t)bin * nblkE + blk;
        u32 slot = mscan[flat] + bsum[flat >> 11] + rank;
        places[slot] = ((u64)((u32)dst & (BKT - 1)) << 32) |
                       (((u32)src << 14) | w14);
    }
}

// per-bucket counting sort -> row_ptr + colw
__global__ void k_bucket(const u64* __restrict__ places,
                         const u32* __restrict__ mscan,
                         const u32* __restrict__ bsum,
                         u32* __restrict__ row_ptr,
                         u32* __restrict__ colw,
                         int N, int E, int B, int nblkE) {
    __shared__ u32 hist[BKT];
    __shared__ u32 excl[BKT];
    __shared__ u32 sdata[256];
    int b = blockIdx.x;
    int t = threadIdx.x;
    int node0 = b * BKT;
    int nnodes = N - node0; if (nnodes > BKT) nnodes = BKT;
    size_t flat0 = (size_t)b * nblkE;
    u32 seg_s = mscan[flat0] + bsum[flat0 >> 11];
    u32 seg_e;
    if (b + 1 < B) {
        size_t f1 = flat0 + nblkE;
        seg_e = mscan[f1] + bsum[f1 >> 11];
    } else {
        seg_e = (u32)(2 * E);
    }
    for (int i = t; i < BKT; i += 256) hist[i] = 0;
    __syncthreads();
    for (u32 j = seg_s + t; j < seg_e; j += 256) {
        u64 pl = places[j];
        atomicAdd(&hist[(u32)(pl >> 32)], 1u);
    }
    __syncthreads();
    // exclusive scan of 512 bins via 256 pair-sums
    u32 a0 = hist[2 * t], a1 = hist[2 * t + 1];
    u32 tsum = a0 + a1;
    sdata[t] = tsum;
    __syncthreads();
    for (int off = 1; off < 256; off <<= 1) {
        u32 x = (t >= off) ? sdata[t - off] : 0u;
        __syncthreads();
        sdata[t] += x;
        __syncthreads();
    }
    u32 texcl = sdata[t] - tsum;
    excl[2 * t] = texcl;
    excl[2 * t + 1] = texcl + a0;
    __syncthreads();
    for (int i = t; i < nnodes; i += 256)
        row_ptr[node0 + i] = seg_s + excl[i];
    if (b == 0 && t == 0) row_ptr[N] = (u32)(2 * E);
    __syncthreads();
    for (u32 j = seg_s + t; j < seg_e; j += 256) {
        u64 pl = places[j];
        u32 loc = atomicAdd(&excl[(u32)(pl >> 32)], 1u);
        colw[seg_s + loc] = (u32)pl;
    }
}

// sum_j x[src_j*64+lane]*w_j over fp16 rows, 8-deep MLP
__device__ __forceinline__ float gather_row_sum(const __half* __restrict__ x,
                                                const u32* __restrict__ colw,
                                                u32 s, u32 e, int lane) {
    float acc = 0.0f;
    for (u32 base = s; base < e; base += 64) {
        u32 m = e - base; if (m > 64u) m = 64u;
        u32 u = 0;
        if ((u32)lane < m) u = colw[base + lane];
        int   cx = (int)(u >> 14);
        float cy = (float)(u & 16383u) * (1.0f / 16384.0f);
        u32 j = 0;
        for (; j + 8 <= m; j += 8) {
            int   s0 = __shfl(cx, (int)j);
            int   s1 = __shfl(cx, (int)j + 1);
            int   s2 = __shfl(cx, (int)j + 2);
            int   s3 = __shfl(cx, (int)j + 3);
            int   s4 = __shfl(cx, (int)j + 4);
            int   s5 = __shfl(cx, (int)j + 5);
            int   s6 = __shfl(cx, (int)j + 6);
            int   s7 = __shfl(cx, (int)j + 7);
            float w0 = __shfl(cy, (int)j);
            float w1 = __shfl(cy, (int)j + 1);
            float w2 = __shfl(cy, (int)j + 2);
            float w3 = __shfl(cy, (int)j + 3);
            float w4 = __shfl(cy, (int)j + 4);
            float w5 = __shfl(cy, (int)j + 5);
            float w6 = __shfl(cy, (int)j + 6);
            float w7 = __shfl(cy, (int)j + 7);
            float v0 = __half2float(x[(size_t)s0 * DIM + lane]);
            float v1 = __half2float(x[(size_t)s1 * DIM + lane]);
            float v2 = __half2float(x[(size_t)s2 * DIM + lane]);
            float v3 = __half2float(x[(size_t)s3 * DIM + lane]);
            float v4 = __half2float(x[(size_t)s4 * DIM + lane]);
            float v5 = __half2float(x[(size_t)s5 * DIM + lane]);
            float v6 = __half2float(x[(size_t)s6 * DIM + lane]);
            float v7 = __half2float(x[(size_t)s7 * DIM + lane]);
            acc += v0 * w0; acc += v1 * w1; acc += v2 * w2; acc += v3 * w3;
            acc += v4 * w4; acc += v5 * w5; acc += v6 * w6; acc += v7 * w7;
        }
        for (; j < m; j++) {
            int   sj = __shfl(cx, (int)j);
            float wj = __shfl(cy, (int)j);
            acc += __half2float(x[(size_t)sj * DIM + lane]) * wj;
        }
    }
    return acc;
}

__global__ void k_conv1(const __half* __restrict__ x0h,
                        const u32* __restrict__ row_ptr,
                        const u32* __restrict__ colw,
                        __half* __restrict__ x1h, int N) {
    int row  = blockIdx.x * 4 + (threadIdx.x >> 6);
    int lane = threadIdx.x & 63;
    if (row >= N) return;
    u32 s = row_ptr[row], e = row_ptr[row + 1];
    float acc = gather_row_sum(x0h, colw, s, e, lane);
    float v = acc / fmaxf((float)(e - s), 1.0f);
    v = (v >= 0.0f) ? v : NEG_SLOPE * v;
    x1h[(size_t)row * DIM + lane] = __float2half(v);
}

__global__ void k_conv2(const __half* __restrict__ x0h,
                        const __half* __restrict__ x1h,
                        const u32* __restrict__ row_ptr,
                        const u32* __restrict__ colw,
                        float* __restrict__ out, int N) {
    int row  = blockIdx.x * 4 + (threadIdx.x >> 6);
    int lane = threadIdx.x & 63;
    if (row >= N) return;
    u32 s = row_ptr[row], e = row_ptr[row + 1];
    float acc = gather_row_sum(x1h, colw, s, e, lane);
    float x2 = acc / fmaxf((float)(e - s), 1.0f);
    x2 = (x2 >= 0.0f) ? x2 : NEG_SLOPE * x2;
    size_t i = (size_t)row * DIM + lane;
    out[i] = __half2float(x0h[i]) + __half2float(x1h[i]) + x2;
}

static inline size_t align16(size_t x) { return (x + 15) & ~(size_t)15; }

extern "C" void kernel_launch(void* const* d_in, const int* in_sizes, int n_in,
                              void* d_out, int out_size, void* d_ws, size_t ws_size,
                              hipStream_t stream) {
    const int N = in_sizes[0] / DIM;      // 200000
    const int E = in_sizes[1] / 2;        // 600000

    const float* emb = (const float*)d_in[0];
    const int*   ei  = (const int*)d_in[1];
    const float* w   = (const float*)d_in[2];
    float*       out = (float*)d_out;

    const int B     = (N + BKT - 1) / BKT;          // 391 buckets
    const int nblkE = (2 * E + TILE - 1) / TILE;    // 586 edge tiles
    const int M     = B * nblkE;                    // 229,126
    const int nb1   = (M + TILE - 1) / TILE;        // 112
    const int rb    = (N + 3) / 4;                  // 50000 norm blocks

    char* ws = (char*)d_ws;
    size_t off = 0;
    __half* x0h    = (__half*)(ws + off); off += align16((size_t)N * DIM * 2);
    __half* x1h    = (__half*)(ws + off); off += align16((size_t)N * DIM * 2);
    u64*    places = (u64*)(ws + off);    off += align16((size_t)2 * E * 8);
    u32*    colw   = (u32*)(ws + off);    off += align16((size_t)2 * E * 4);
    u32*    mat    = (u32*)(ws + off);    off += align16((size_t)M * 4);
    u32*    mscan  = (u32*)(ws + off);    off += align16((size_t)M * 4);
    u32*    row_ptr= (u32*)(ws + off);    off += align16((size_t)(N + 1) * 4);
    u32*    bsum   = (u32*)(ws + off);    off += align16(256 * 4);

    k_norm_hist<<<rb + nblkE, 256, 0, stream>>>(emb, x0h, ei, mat, N, E, rb, B, nblkE);
    k_scan1<<<nb1, 256, 0, stream>>>(mat, mscan, bsum, M);
    k_scan2<<<1, 256, 0, stream>>>(bsum, nb1);
    k_place<<<nblkE, 256, 0, stream>>>(ei, w, mscan, bsum, places, E, nblkE);
    k_bucket<<<B, 256, 0, stream>>>(places, mscan, bsum, row_ptr, colw, N, E, B, nblkE);

    k_conv1<<<rb, 256, 0, stream>>>(x0h, row_ptr, colw, x1h, N);
    k_conv2<<<rb, 256, 0, stream>>>(x0h, x1h, row_ptr, colw, out, N);
}

// Round 7
// 234.737 us; speedup vs baseline: 3.2476x; 1.4089x over previous
//
#include <hip/hip_runtime.h>
#include <hip/hip_fp16.h>

#define DIM 64
#define NEG_SLOPE 0.01f
#define BKT 512          // nodes per bucket (LDS bins in k_bucket)
#define TILE 2048        // edges per block in hist/place (scan tile too)

typedef unsigned u32;
typedef unsigned long long u64;

// ---------------------------------------------------------------------------
// Round 7: convs were latency-bound at MLP~1 (avg deg 6 < unroll 8 -> serial
// tail loop; ~4k cyc/row dependent-gather chain). New mapping: 8 rows/wave,
// 8 lanes/row, 16 B (8-half) load per lane; chunk of 8 colw entries fully
// unrolled with zero-padding -> 8 independent gathers in flight per group,
// 8 groups concurrent. Build phase (atomic-free bucket CSR) unchanged.
// ---------------------------------------------------------------------------

__global__ void k_norm_hist(const float* __restrict__ emb,
                            __half* __restrict__ x0h,
                            const int* __restrict__ p,
                            u32* __restrict__ mat,
                            int N, int E, int rb, int B, int nblkE) {
    if ((int)blockIdx.x < rb) {
        int row  = blockIdx.x * 4 + (threadIdx.x >> 6);
        int lane = threadIdx.x & 63;
        if (row >= N) return;
        float v = emb[(size_t)row * DIM + lane];
        float s = v * v;
        #pragma unroll
        for (int m = 32; m; m >>= 1) s += __shfl_xor(s, m, 64);
        float inv = 1.0f / fmaxf(sqrtf(s), 1e-12f);
        x0h[(size_t)row * DIM + lane] = __float2half(v * inv);
    } else {
        __shared__ u32 hist[BKT];
        int blk = blockIdx.x - rb;
        int t = threadIdx.x;
        for (int i = t; i < B; i += 256) hist[i] = 0;
        __syncthreads();
        int base = blk * TILE;
        #pragma unroll
        for (int k = 0; k < TILE / 256; k++) {
            int e = base + k * 256 + t;
            if (e < 2 * E) {
                int dst = (e < E) ? p[e + E] : p[e - E];
                atomicAdd(&hist[(u32)dst >> 9], 1u);
            }
        }
        __syncthreads();
        for (int i = t; i < B; i += 256) mat[(size_t)i * nblkE + blk] = hist[i];
    }
}

__global__ void k_scan1(const u32* __restrict__ in, u32* __restrict__ out,
                        u32* __restrict__ bsum, int M) {
    __shared__ u32 sdata[256];
    int t = threadIdx.x;
    int base = blockIdx.x * TILE + t * 8;
    u32 v[8]; u32 tsum = 0;
    #pragma unroll
    for (int k = 0; k < 8; k++) {
        int i = base + k;
        v[k] = (i < M) ? in[i] : 0u;
        tsum += v[k];
    }
    sdata[t] = tsum;
    __syncthreads();
    for (int off = 1; off < 256; off <<= 1) {
        u32 x = (t >= off) ? sdata[t - off] : 0u;
        __syncthreads();
        sdata[t] += x;
        __syncthreads();
    }
    u32 run = sdata[t] - tsum;
    if (t == 255) bsum[blockIdx.x] = sdata[255];
    #pragma unroll
    for (int k = 0; k < 8; k++) {
        int i = base + k;
        if (i < M) out[i] = run;
        run += v[k];
    }
}

__global__ void k_scan2(u32* __restrict__ bsum, int nb) {
    __shared__ u32 sdata[256];
    int t = threadIdx.x;
    u32 v = (t < nb) ? bsum[t] : 0u;
    sdata[t] = v;
    __syncthreads();
    for (int off = 1; off < 256; off <<= 1) {
        u32 x = (t >= off) ? sdata[t - off] : 0u;
        __syncthreads();
        sdata[t] += x;
        __syncthreads();
    }
    if (t < nb) bsum[t] = sdata[t] - v;
}

__global__ void k_place(const int* __restrict__ p, const float* __restrict__ w,
                        const u32* __restrict__ mscan,
                        const u32* __restrict__ bsum,
                        u64* __restrict__ places, int E, int nblkE) {
    __shared__ u32 cur[BKT];
    int blk = blockIdx.x;
    int t = threadIdx.x;
    for (int i = t; i < BKT; i += 256) cur[i] = 0;
    __syncthreads();
    int base = blk * TILE;
    #pragma unroll
    for (int k = 0; k < TILE / 256; k++) {
        int e = base + k * 256 + t;
        if (e >= 2 * E) continue;
        int src = p[e];
        int dst = (e < E) ? p[e + E] : p[e - E];
        u32 bin = (u32)dst >> 9;
        u32 w14 = (u32)(w[e] * 16384.0f + 0.5f);
        if (w14 > 16383u) w14 = 16383u;
        u32 rank = atomicAdd(&cur[bin], 1u);
        size_t flat = (size_t)bin * nblkE + blk;
        u32 slot = mscan[flat] + bsum[flat >> 11] + rank;
        places[slot] = ((u64)((u32)dst & (BKT - 1)) << 32) |
                       (((u32)src << 14) | w14);
    }
}

__global__ void k_bucket(const u64* __restrict__ places,
                         const u32* __restrict__ mscan,
                         const u32* __restrict__ bsum,
                         u32* __restrict__ row_ptr,
                         u32* __restrict__ colw,
                         int N, int E, int B, int nblkE) {
    __shared__ u32 hist[BKT];
    __shared__ u32 excl[BKT];
    __shared__ u32 sdata[256];
    int b = blockIdx.x;
    int t = threadIdx.x;
    int node0 = b * BKT;
    int nnodes = N - node0; if (nnodes > BKT) nnodes = BKT;
    size_t flat0 = (size_t)b * nblkE;
    u32 seg_s = mscan[flat0] + bsum[flat0 >> 11];
    u32 seg_e;
    if (b + 1 < B) {
        size_t f1 = flat0 + nblkE;
        seg_e = mscan[f1] + bsum[f1 >> 11];
    } else {
        seg_e = (u32)(2 * E);
    }
    for (int i = t; i < BKT; i += 256) hist[i] = 0;
    __syncthreads();
    for (u32 j = seg_s + t; j < seg_e; j += 256) {
        u64 pl = places[j];
        atomicAdd(&hist[(u32)(pl >> 32)], 1u);
    }
    __syncthreads();
    u32 a0 = hist[2 * t], a1 = hist[2 * t + 1];
    u32 tsum = a0 + a1;
    sdata[t] = tsum;
    __syncthreads();
    for (int off = 1; off < 256; off <<= 1) {
        u32 x = (t >= off) ? sdata[t - off] : 0u;
        __syncthreads();
        sdata[t] += x;
        __syncthreads();
    }
    u32 texcl = sdata[t] - tsum;
    excl[2 * t] = texcl;
    excl[2 * t + 1] = texcl + a0;
    __syncthreads();
    for (int i = t; i < nnodes; i += 256)
        row_ptr[node0 + i] = seg_s + excl[i];
    if (b == 0 && t == 0) row_ptr[N] = (u32)(2 * E);
    __syncthreads();
    for (u32 j = seg_s + t; j < seg_e; j += 256) {
        u64 pl = places[j];
        u32 loc = atomicAdd(&excl[(u32)(pl >> 32)], 1u);
        colw[seg_s + loc] = (u32)pl;
    }
}

// --- conv: 8 rows/wave, 8 lanes/row, lane covers dims [sub*8, sub*8+8) ----

__device__ __forceinline__ void gather8(const __half* __restrict__ x,
                                        const u32* __restrict__ colw,
                                        u32 s, u32 e, int g, int sub,
                                        float acc[8]) {
    for (u32 base = s; base < e; base += 8) {
        u32 u = 0;
        if (base + (u32)sub < e) u = colw[base + sub];
        int   cx = (int)(u >> 14);
        float cy = (float)(u & 16383u) * (1.0f / 16384.0f);
        #pragma unroll
        for (int j = 0; j < 8; j++) {
            int   sj = __shfl(cx, (g << 3) | j, 64);
            float wj = __shfl(cy, (g << 3) | j, 64);
            uint4 q = *(const uint4*)(x + (size_t)sj * DIM + sub * 8);
            const __half2* hp = (const __half2*)&q;
            #pragma unroll
            for (int k = 0; k < 4; k++) {
                float2 f = __half22float2(hp[k]);
                acc[2 * k]     += f.x * wj;
                acc[2 * k + 1] += f.y * wj;
            }
        }
    }
}

__global__ void k_conv1(const __half* __restrict__ x0h,
                        const u32* __restrict__ row_ptr,
                        const u32* __restrict__ colw,
                        __half* __restrict__ x1h, int N) {
    int wave = (blockIdx.x * 256 + threadIdx.x) >> 6;
    int g    = (threadIdx.x >> 3) & 7;
    int sub  = threadIdx.x & 7;
    int row  = wave * 8 + g;
    if (row >= N) return;
    u32 s = row_ptr[row], e = row_ptr[row + 1];
    float acc[8] = {0, 0, 0, 0, 0, 0, 0, 0};
    gather8(x0h, colw, s, e, g, sub, acc);
    float rdeno = 1.0f / fmaxf((float)(e - s), 1.0f);
    __half2 hv[4];
    #pragma unroll
    for (int k = 0; k < 4; k++) {
        float v0 = acc[2 * k] * rdeno;
        float v1 = acc[2 * k + 1] * rdeno;
        v0 = (v0 >= 0.0f) ? v0 : NEG_SLOPE * v0;
        v1 = (v1 >= 0.0f) ? v1 : NEG_SLOPE * v1;
        hv[k] = __floats2half2_rn(v0, v1);
    }
    *(uint4*)(x1h + (size_t)row * DIM + sub * 8) = *(const uint4*)hv;
}

__global__ void k_conv2(const __half* __restrict__ x0h,
                        const __half* __restrict__ x1h,
                        const u32* __restrict__ row_ptr,
                        const u32* __restrict__ colw,
                        float* __restrict__ out, int N) {
    int wave = (blockIdx.x * 256 + threadIdx.x) >> 6;
    int g    = (threadIdx.x >> 3) & 7;
    int sub  = threadIdx.x & 7;
    int row  = wave * 8 + g;
    if (row >= N) return;
    u32 s = row_ptr[row], e = row_ptr[row + 1];
    float acc[8] = {0, 0, 0, 0, 0, 0, 0, 0};
    gather8(x1h, colw, s, e, g, sub, acc);
    float rdeno = 1.0f / fmaxf((float)(e - s), 1.0f);
    uint4 q0 = *(const uint4*)(x0h + (size_t)row * DIM + sub * 8);
    uint4 q1 = *(const uint4*)(x1h + (size_t)row * DIM + sub * 8);
    const __half2* h0 = (const __half2*)&q0;
    const __half2* h1 = (const __half2*)&q1;
    float r[8];
    #pragma unroll
    for (int k = 0; k < 4; k++) {
        float2 a = __half22float2(h0[k]);
        float2 b = __half22float2(h1[k]);
        float x2a = acc[2 * k] * rdeno;
        float x2b = acc[2 * k + 1] * rdeno;
        x2a = (x2a >= 0.0f) ? x2a : NEG_SLOPE * x2a;
        x2b = (x2b >= 0.0f) ? x2b : NEG_SLOPE * x2b;
        r[2 * k]     = a.x + b.x + x2a;
        r[2 * k + 1] = a.y + b.y + x2b;
    }
    float* op = out + (size_t)row * DIM + sub * 8;
    *(float4*)(op)     = make_float4(r[0], r[1], r[2], r[3]);
    *(float4*)(op + 4) = make_float4(r[4], r[5], r[6], r[7]);
}

static inline size_t align16(size_t x) { return (x + 15) & ~(size_t)15; }

extern "C" void kernel_launch(void* const* d_in, const int* in_sizes, int n_in,
                              void* d_out, int out_size, void* d_ws, size_t ws_size,
                              hipStream_t stream) {
    const int N = in_sizes[0] / DIM;      // 200000
    const int E = in_sizes[1] / 2;        // 600000

    const float* emb = (const float*)d_in[0];
    const int*   ei  = (const int*)d_in[1];
    const float* w   = (const float*)d_in[2];
    float*       out = (float*)d_out;

    const int B     = (N + BKT - 1) / BKT;          // 391 buckets
    const int nblkE = (2 * E + TILE - 1) / TILE;    // 586 edge tiles
    const int M     = B * nblkE;                    // 229,126
    const int nb1   = (M + TILE - 1) / TILE;        // 112
    const int rb    = (N + 3) / 4;                  // 50000 norm blocks
    const int cvb   = (N + 31) / 32;                // conv blocks: 32 rows/block

    char* ws = (char*)d_ws;
    size_t off = 0;
    __half* x0h    = (__half*)(ws + off); off += align16((size_t)N * DIM * 2);
    __half* x1h    = (__half*)(ws + off); off += align16((size_t)N * DIM * 2);
    u64*    places = (u64*)(ws + off);    off += align16((size_t)2 * E * 8);
    u32*    colw   = (u32*)(ws + off);    off += align16((size_t)2 * E * 4);
    u32*    mat    = (u32*)(ws + off);    off += align16((size_t)M * 4);
    u32*    mscan  = (u32*)(ws + off);    off += align16((size_t)M * 4);
    u32*    row_ptr= (u32*)(ws + off);    off += align16((size_t)(N + 1) * 4);
    u32*    bsum   = (u32*)(ws + off);    off += align16(256 * 4);

    k_norm_hist<<<rb + nblkE, 256, 0, stream>>>(emb, x0h, ei, mat, N, E, rb, B, nblkE);
    k_scan1<<<nb1, 256, 0, stream>>>(mat, mscan, bsum, M);
    k_scan2<<<1, 256, 0, stream>>>(bsum, nb1);
    k_place<<<nblkE, 256, 0, stream>>>(ei, w, mscan, bsum, places, E, nblkE);
    k_bucket<<<B, 256, 0, stream>>>(places, mscan, bsum, row_ptr, colw, N, E, B, nblkE);

    k_conv1<<<cvb, 256, 0, stream>>>(x0h, row_ptr, colw, x1h, N);
    k_conv2<<<cvb, 256, 0, stream>>>(x0h, x1h, row_ptr, colw, out, N);
}

// Round 8
// 226.258 us; speedup vs baseline: 3.3693x; 1.0375x over previous
//
#include <hip/hip_runtime.h>
#include <hip/hip_fp16.h>

#define DIM 64
#define NEG_SLOPE 0.01f
#define BKT 512          // nodes per bucket (LDS bins in k_bucket)
#define TILE 2048        // edges per block in hist/place (scan tile too)

typedef unsigned u32;
typedef unsigned long long u64;

// ---------------------------------------------------------------------------
// Round 8: norm_hist was VALU/wave-starved (1 row/wave, scalar lanes, 6-shfl
// chain). Now: float4/lane, 16 lanes/row, 4 rows/wave, 4-step reduce.
// bsum folded into mscan by k_scanfix -> place/bucket lose a dependent
// random load on the critical path. Convs unchanged (8 rows/wave mapping).
// ---------------------------------------------------------------------------

__global__ void k_norm_hist(const float* __restrict__ emb,
                            __half* __restrict__ x0h,
                            const int* __restrict__ p,
                            u32* __restrict__ mat,
                            int N, int E, int rb, int B, int nblkE) {
    if ((int)blockIdx.x < rb) {
        int lane = threadIdx.x & 63;
        int row  = blockIdx.x * 16 + (threadIdx.x >> 6) * 4 + (lane >> 4);
        int l16  = lane & 15;
        if (row >= N) return;
        float4 v = *(const float4*)(emb + (size_t)row * DIM + l16 * 4);
        float s = v.x * v.x + v.y * v.y + v.z * v.z + v.w * v.w;
        #pragma unroll
        for (int m = 1; m < 16; m <<= 1) s += __shfl_xor(s, m, 64);
        float inv = 1.0f / fmaxf(sqrtf(s), 1e-12f);
        union { uint2 u; __half2 h[2]; } pk;
        pk.h[0] = __floats2half2_rn(v.x * inv, v.y * inv);
        pk.h[1] = __floats2half2_rn(v.z * inv, v.w * inv);
        *(uint2*)(x0h + (size_t)row * DIM + l16 * 4) = pk.u;
    } else {
        __shared__ u32 hist[BKT];
        int blk = blockIdx.x - rb;
        int t = threadIdx.x;
        for (int i = t; i < B; i += 256) hist[i] = 0;
        __syncthreads();
        int base = blk * TILE;
        #pragma unroll
        for (int k = 0; k < TILE / 256; k++) {
            int e = base + k * 256 + t;
            if (e < 2 * E) {
                int dst = (e < E) ? p[e + E] : p[e - E];
                atomicAdd(&hist[(u32)dst >> 9], 1u);
            }
        }
        __syncthreads();
        for (int i = t; i < B; i += 256) mat[(size_t)i * nblkE + blk] = hist[i];
    }
}

__global__ void k_scan1(const u32* __restrict__ in, u32* __restrict__ out,
                        u32* __restrict__ bsum, int M) {
    __shared__ u32 sdata[256];
    int t = threadIdx.x;
    int base = blockIdx.x * TILE + t * 8;
    u32 v[8]; u32 tsum = 0;
    #pragma unroll
    for (int k = 0; k < 8; k++) {
        int i = base + k;
        v[k] = (i < M) ? in[i] : 0u;
        tsum += v[k];
    }
    sdata[t] = tsum;
    __syncthreads();
    for (int off = 1; off < 256; off <<= 1) {
        u32 x = (t >= off) ? sdata[t - off] : 0u;
        __syncthreads();
        sdata[t] += x;
        __syncthreads();
    }
    u32 run = sdata[t] - tsum;
    if (t == 255) bsum[blockIdx.x] = sdata[255];
    #pragma unroll
    for (int k = 0; k < 8; k++) {
        int i = base + k;
        if (i < M) out[i] = run;
        run += v[k];
    }
}

__global__ void k_scan2(u32* __restrict__ bsum, int nb) {
    __shared__ u32 sdata[256];
    int t = threadIdx.x;
    u32 v = (t < nb) ? bsum[t] : 0u;
    sdata[t] = v;
    __syncthreads();
    for (int off = 1; off < 256; off <<= 1) {
        u32 x = (t >= off) ? sdata[t - off] : 0u;
        __syncthreads();
        sdata[t] += x;
        __syncthreads();
    }
    if (t < nb) bsum[t] = sdata[t] - v;
}

// fold block offsets into mscan so consumers do ONE load per lookup
__global__ void k_scanfix(u32* __restrict__ mscan,
                          const u32* __restrict__ bsum, int M) {
    int i = blockIdx.x * 256 + threadIdx.x;
    if (i >= M) return;
    mscan[i] += bsum[i >> 11];
}

__global__ void k_place(const int* __restrict__ p, const float* __restrict__ w,
                        const u32* __restrict__ mscan,
                        u64* __restrict__ places, int E, int nblkE) {
    __shared__ u32 cur[BKT];
    int blk = blockIdx.x;
    int t = threadIdx.x;
    for (int i = t; i < BKT; i += 256) cur[i] = 0;
    __syncthreads();
    int base = blk * TILE;
    #pragma unroll
    for (int k = 0; k < TILE / 256; k++) {
        int e = base + k * 256 + t;
        if (e >= 2 * E) continue;
        int src = p[e];
        int dst = (e < E) ? p[e + E] : p[e - E];
        u32 bin = (u32)dst >> 9;
        u32 w14 = (u32)(w[e] * 16384.0f + 0.5f);
        if (w14 > 16383u) w14 = 16383u;
        u32 rank = atomicAdd(&cur[bin], 1u);
        u32 slot = mscan[(size_t)bin * nblkE + blk] + rank;
        places[slot] = ((u64)((u32)dst & (BKT - 1)) << 32) |
                       (((u32)src << 14) | w14);
    }
}

__global__ void k_bucket(const u64* __restrict__ places,
                         const u32* __restrict__ mscan,
                         u32* __restrict__ row_ptr,
                         u32* __restrict__ colw,
                         int N, int E, int B, int nblkE) {
    __shared__ u32 hist[BKT];
    __shared__ u32 excl[BKT];
    __shared__ u32 sdata[256];
    int b = blockIdx.x;
    int t = threadIdx.x;
    int node0 = b * BKT;
    int nnodes = N - node0; if (nnodes > BKT) nnodes = BKT;
    size_t flat0 = (size_t)b * nblkE;
    u32 seg_s = mscan[flat0];
    u32 seg_e = (b + 1 < B) ? mscan[flat0 + nblkE] : (u32)(2 * E);
    for (int i = t; i < BKT; i += 256) hist[i] = 0;
    __syncthreads();
    for (u32 j = seg_s + t; j < seg_e; j += 256) {
        u64 pl = places[j];
        atomicAdd(&hist[(u32)(pl >> 32)], 1u);
    }
    __syncthreads();
    u32 a0 = hist[2 * t], a1 = hist[2 * t + 1];
    u32 tsum = a0 + a1;
    sdata[t] = tsum;
    __syncthreads();
    for (int off = 1; off < 256; off <<= 1) {
        u32 x = (t >= off) ? sdata[t - off] : 0u;
        __syncthreads();
        sdata[t] += x;
        __syncthreads();
    }
    u32 texcl = sdata[t] - tsum;
    excl[2 * t] = texcl;
    excl[2 * t + 1] = texcl + a0;
    __syncthreads();
    for (int i = t; i < nnodes; i += 256)
        row_ptr[node0 + i] = seg_s + excl[i];
    if (b == 0 && t == 0) row_ptr[N] = (u32)(2 * E);
    __syncthreads();
    for (u32 j = seg_s + t; j < seg_e; j += 256) {
        u64 pl = places[j];
        u32 loc = atomicAdd(&excl[(u32)(pl >> 32)], 1u);
        colw[seg_s + loc] = (u32)pl;
    }
}

// --- conv: 8 rows/wave, 8 lanes/row, lane covers dims [sub*8, sub*8+8) ----

__device__ __forceinline__ void gather8(const __half* __restrict__ x,
                                        const u32* __restrict__ colw,
                                        u32 s, u32 e, int g, int sub,
                                        float acc[8]) {
    for (u32 base = s; base < e; base += 8) {
        u32 u = 0;
        if (base + (u32)sub < e) u = colw[base + sub];
        int   cx = (int)(u >> 14);
        float cy = (float)(u & 16383u) * (1.0f / 16384.0f);
        #pragma unroll
        for (int j = 0; j < 8; j++) {
            int   sj = __shfl(cx, (g << 3) | j, 64);
            float wj = __shfl(cy, (g << 3) | j, 64);
            uint4 q = *(const uint4*)(x + (size_t)sj * DIM + sub * 8);
            const __half2* hp = (const __half2*)&q;
            #pragma unroll
            for (int k = 0; k < 4; k++) {
                float2 f = __half22float2(hp[k]);
                acc[2 * k]     += f.x * wj;
                acc[2 * k + 1] += f.y * wj;
            }
        }
    }
}

__global__ void k_conv1(const __half* __restrict__ x0h,
                        const u32* __restrict__ row_ptr,
                        const u32* __restrict__ colw,
                        __half* __restrict__ x1h, int N) {
    int wave = (blockIdx.x * 256 + threadIdx.x) >> 6;
    int g    = (threadIdx.x >> 3) & 7;
    int sub  = threadIdx.x & 7;
    int row  = wave * 8 + g;
    if (row >= N) return;
    u32 s = row_ptr[row], e = row_ptr[row + 1];
    float acc[8] = {0, 0, 0, 0, 0, 0, 0, 0};
    gather8(x0h, colw, s, e, g, sub, acc);
    float rdeno = 1.0f / fmaxf((float)(e - s), 1.0f);
    __half2 hv[4];
    #pragma unroll
    for (int k = 0; k < 4; k++) {
        float v0 = acc[2 * k] * rdeno;
        float v1 = acc[2 * k + 1] * rdeno;
        v0 = (v0 >= 0.0f) ? v0 : NEG_SLOPE * v0;
        v1 = (v1 >= 0.0f) ? v1 : NEG_SLOPE * v1;
        hv[k] = __floats2half2_rn(v0, v1);
    }
    *(uint4*)(x1h + (size_t)row * DIM + sub * 8) = *(const uint4*)hv;
}

__global__ void k_conv2(const __half* __restrict__ x0h,
                        const __half* __restrict__ x1h,
                        const u32* __restrict__ row_ptr,
                        const u32* __restrict__ colw,
                        float* __restrict__ out, int N) {
    int wave = (blockIdx.x * 256 + threadIdx.x) >> 6;
    int g    = (threadIdx.x >> 3) & 7;
    int sub  = threadIdx.x & 7;
    int row  = wave * 8 + g;
    if (row >= N) return;
    u32 s = row_ptr[row], e = row_ptr[row + 1];
    float acc[8] = {0, 0, 0, 0, 0, 0, 0, 0};
    gather8(x1h, colw, s, e, g, sub, acc);
    float rdeno = 1.0f / fmaxf((float)(e - s), 1.0f);
    uint4 q0 = *(const uint4*)(x0h + (size_t)row * DIM + sub * 8);
    uint4 q1 = *(const uint4*)(x1h + (size_t)row * DIM + sub * 8);
    const __half2* h0 = (const __half2*)&q0;
    const __half2* h1 = (const __half2*)&q1;
    float r[8];
    #pragma unroll
    for (int k = 0; k < 4; k++) {
        float2 a = __half22float2(h0[k]);
        float2 b = __half22float2(h1[k]);
        float x2a = acc[2 * k] * rdeno;
        float x2b = acc[2 * k + 1] * rdeno;
        x2a = (x2a >= 0.0f) ? x2a : NEG_SLOPE * x2a;
        x2b = (x2b >= 0.0f) ? x2b : NEG_SLOPE * x2b;
        r[2 * k]     = a.x + b.x + x2a;
        r[2 * k + 1] = a.y + b.y + x2b;
    }
    float* op = out + (size_t)row * DIM + sub * 8;
    *(float4*)(op)     = make_float4(r[0], r[1], r[2], r[3]);
    *(float4*)(op + 4) = make_float4(r[4], r[5], r[6], r[7]);
}

static inline size_t align16(size_t x) { return (x + 15) & ~(size_t)15; }

extern "C" void kernel_launch(void* const* d_in, const int* in_sizes, int n_in,
                              void* d_out, int out_size, void* d_ws, size_t ws_size,
                              hipStream_t stream) {
    const int N = in_sizes[0] / DIM;      // 200000
    const int E = in_sizes[1] / 2;        // 600000

    const float* emb = (const float*)d_in[0];
    const int*   ei  = (const int*)d_in[1];
    const float* w   = (const float*)d_in[2];
    float*       out = (float*)d_out;

    const int B     = (N + BKT - 1) / BKT;          // 391 buckets
    const int nblkE = (2 * E + TILE - 1) / TILE;    // 586 edge tiles
    const int M     = B * nblkE;                    // 229,126
    const int nb1   = (M + TILE - 1) / TILE;        // 112
    const int rb    = (N + 15) / 16;                // 12500 norm blocks
    const int cvb   = (N + 31) / 32;                // conv blocks: 32 rows/block

    char* ws = (char*)d_ws;
    size_t off = 0;
    __half* x0h    = (__half*)(ws + off); off += align16((size_t)N * DIM * 2);
    __half* x1h    = (__half*)(ws + off); off += align16((size_t)N * DIM * 2);
    u64*    places = (u64*)(ws + off);    off += align16((size_t)2 * E * 8);
    u32*    colw   = (u32*)(ws + off);    off += align16((size_t)2 * E * 4);
    u32*    mat    = (u32*)(ws + off);    off += align16((size_t)M * 4);
    u32*    mscan  = (u32*)(ws + off);    off += align16((size_t)M * 4);
    u32*    row_ptr= (u32*)(ws + off);    off += align16((size_t)(N + 1) * 4);
    u32*    bsum   = (u32*)(ws + off);    off += align16(256 * 4);

    k_norm_hist<<<rb + nblkE, 256, 0, stream>>>(emb, x0h, ei, mat, N, E, rb, B, nblkE);
    k_scan1<<<nb1, 256, 0, stream>>>(mat, mscan, bsum, M);
    k_scan2<<<1, 256, 0, stream>>>(bsum, nb1);
    k_scanfix<<<(M + 255) / 256, 256, 0, stream>>>(mscan, bsum, M);
    k_place<<<nblkE, 256, 0, stream>>>(ei, w, mscan, places, E, nblkE);
    k_bucket<<<B, 256, 0, stream>>>(places, mscan, row_ptr, colw, N, E, B, nblkE);

    k_conv1<<<cvb, 256, 0, stream>>>(x0h, row_ptr, colw, x1h, N);
    k_conv2<<<cvb, 256, 0, stream>>>(x0h, x1h, row_ptr, colw, out, N);
}